// Round 7
// baseline (304.116 us; speedup 1.0000x reference)
//
#include <hip/hip_runtime.h>
#include <hip/hip_bf16.h>

#define N_NODES 50000
#define N_EDGES 640000
#define D 128
#define NPAD 50048   // 782 * 64; also 391 * 128
#define LAYERS 3
#define SCAN_NB 196  // ceil(50000/256)

#define NSLAB 8
#define SLAB_HB (N_NODES * 16)   // shorts per hb slab (1.6 MB)
#define SLAB_Z  (NPAD * 16)      // shorts per z slab

typedef __attribute__((ext_vector_type(4))) float f32x4;
typedef __attribute__((ext_vector_type(8))) short bf16x8;
typedef __attribute__((ext_vector_type(4))) short bf16x4;

static __device__ __forceinline__ short f2bf(float f) {
    union { float f; unsigned u; } x; x.f = f;
    unsigned r = x.u + 0x7fffu + ((x.u >> 16) & 1u);  // RNE
    return (short)(r >> 16);
}
static __device__ __forceinline__ float bf2f(short s) {
    union { unsigned u; float f; } x; x.u = ((unsigned)(unsigned short)s) << 16;
    return x.f;
}

// ---------------- hb(8-sliced) = bf16(x):  hb[s][node][16] ----------------
__global__ void init_kernel(const float* __restrict__ x, short* __restrict__ hb) {
    int t = blockIdx.x * 256 + threadIdx.x;   // t over N_NODES*16 groups of 8 feats
    if (t >= N_NODES * 16) return;
    int node = t >> 4, fg = t & 15;
    int s = fg >> 1, w = (fg & 1) * 8;
    const float* xp = x + (size_t)node * D + fg * 8;
    f32x4 a = *(const f32x4*)(xp);
    f32x4 b = *(const f32x4*)(xp + 4);
    bf16x8 p;
    p[0] = f2bf(a.x); p[1] = f2bf(a.y); p[2] = f2bf(a.z); p[3] = f2bf(a.w);
    p[4] = f2bf(b.x); p[5] = f2bf(b.y); p[6] = f2bf(b.z); p[7] = f2bf(b.w);
    *(bf16x8*)(hb + (size_t)s * SLAB_HB + (size_t)node * 16 + w) = p;
}

// ---------------- weights: wt[m][c][k] = bf16(W[m][k][c]) ----------------
__global__ void prepw_kernel(const float* __restrict__ W1, const float* __restrict__ W2,
                             short* __restrict__ wt) {
    int t = blockIdx.x * 256 + threadIdx.x;
    if (t >= 6 * 16384) return;
    int m = t >> 14, rem = t & 16383;
    int c = rem >> 7, k = rem & 127;
    const float* src = (m < 3) ? (W1 + m * 16384) : (W2 + (m - 3) * 16384);
    wt[m * 16384 + c * 128 + k] = f2bf(src[k * 128 + c]);
}

// ---------------- CSR build ----------------
__global__ void hist_kernel(const int* __restrict__ dst, int* __restrict__ deg) {
    int e = blockIdx.x * 256 + threadIdx.x;
    if (e < N_EDGES) atomicAdd(&deg[dst[e]], 1);
}

__global__ void scan1_kernel(const int* __restrict__ deg, int* __restrict__ rs,
                             int* __restrict__ bsum) {
    __shared__ int tmp[256];
    int i = blockIdx.x * 256 + threadIdx.x;
    int v = (i < N_NODES) ? deg[i] : 0;
    tmp[threadIdx.x] = v;
    __syncthreads();
    for (int off = 1; off < 256; off <<= 1) {
        int t = (threadIdx.x >= off) ? tmp[threadIdx.x - off] : 0;
        __syncthreads();
        tmp[threadIdx.x] += t;
        __syncthreads();
    }
    if (i < N_NODES) rs[i] = tmp[threadIdx.x] - v;  // exclusive
    if (threadIdx.x == 255) bsum[blockIdx.x] = tmp[255];
}

__global__ void scan2_kernel(int* __restrict__ bsum) {
    __shared__ int tmp[256];
    int v = (threadIdx.x < SCAN_NB) ? bsum[threadIdx.x] : 0;
    tmp[threadIdx.x] = v;
    __syncthreads();
    for (int off = 1; off < 256; off <<= 1) {
        int t = (threadIdx.x >= off) ? tmp[threadIdx.x - off] : 0;
        __syncthreads();
        tmp[threadIdx.x] += t;
        __syncthreads();
    }
    if (threadIdx.x < SCAN_NB) bsum[threadIdx.x] = tmp[threadIdx.x] - v;  // exclusive
}

__global__ void scan3_kernel(int* __restrict__ rs, const int* __restrict__ bsum) {
    int i = blockIdx.x * 256 + threadIdx.x;
    if (i < N_NODES) rs[i] += bsum[blockIdx.x];
}

__global__ void fill_kernel(const int* __restrict__ src, const int* __restrict__ dst,
                            const int* __restrict__ rs, int* __restrict__ cursor,
                            int* __restrict__ col) {
    int e = blockIdx.x * 256 + threadIdx.x;
    if (e >= N_EDGES) return;
    int d = dst[e];
    int p = atomicAdd(&cursor[d], 1);
    col[rs[d] + p] = src[e];
}

// ---------------- XCD-local 8-sliced aggregate + GIN prep ----------------
// slice = blockIdx&7 -> one 1.6MB slab per XCD (round-robin dispatch).
// z stores and col loads are NON-TEMPORAL so the slab stays L2-resident.
// 2 lanes/node (16B each), 128 nodes/block, 8 neighbors in flight.
__global__ __launch_bounds__(256) void agg_kernel(const short* __restrict__ hb,
                                                  const int* __restrict__ rs,
                                                  const int* __restrict__ deg,
                                                  const int* __restrict__ col,
                                                  const float* __restrict__ epsArr, int layer,
                                                  short* __restrict__ z) {
    int b = blockIdx.x;
    int slice = b & 7;
    int chunk = b >> 3;                  // 0..390
    int t = threadIdx.x;
    int g = t >> 1, lane2 = t & 1;
    int node = chunk * 128 + g;          // < NPAD
    const short* tab = hb + (size_t)slice * SLAB_HB;
    bf16x8 o;
    if (node < N_NODES) {
        float acc[8] = {0.f, 0.f, 0.f, 0.f, 0.f, 0.f, 0.f, 0.f};
        int start = rs[node], dg = deg[node];
        const int* cp = col + start;
        int base = 0;
        for (; base + 8 <= dg; base += 8) {
            int c0 = __builtin_nontemporal_load(cp + base + 0);
            int c1 = __builtin_nontemporal_load(cp + base + 1);
            int c2 = __builtin_nontemporal_load(cp + base + 2);
            int c3 = __builtin_nontemporal_load(cp + base + 3);
            int c4 = __builtin_nontemporal_load(cp + base + 4);
            int c5 = __builtin_nontemporal_load(cp + base + 5);
            int c6 = __builtin_nontemporal_load(cp + base + 6);
            int c7 = __builtin_nontemporal_load(cp + base + 7);
            bf16x8 v0 = *(const bf16x8*)(tab + (size_t)c0 * 16 + lane2 * 8);
            bf16x8 v1 = *(const bf16x8*)(tab + (size_t)c1 * 16 + lane2 * 8);
            bf16x8 v2 = *(const bf16x8*)(tab + (size_t)c2 * 16 + lane2 * 8);
            bf16x8 v3 = *(const bf16x8*)(tab + (size_t)c3 * 16 + lane2 * 8);
            bf16x8 v4 = *(const bf16x8*)(tab + (size_t)c4 * 16 + lane2 * 8);
            bf16x8 v5 = *(const bf16x8*)(tab + (size_t)c5 * 16 + lane2 * 8);
            bf16x8 v6 = *(const bf16x8*)(tab + (size_t)c6 * 16 + lane2 * 8);
            bf16x8 v7 = *(const bf16x8*)(tab + (size_t)c7 * 16 + lane2 * 8);
#pragma unroll
            for (int e = 0; e < 8; ++e)
                acc[e] += ((bf2f(v0[e]) + bf2f(v1[e])) + (bf2f(v2[e]) + bf2f(v3[e])))
                        + ((bf2f(v4[e]) + bf2f(v5[e])) + (bf2f(v6[e]) + bf2f(v7[e])));
        }
        for (; base < dg; ++base) {
            int c = __builtin_nontemporal_load(cp + base);
            bf16x8 v = *(const bf16x8*)(tab + (size_t)c * 16 + lane2 * 8);
#pragma unroll
            for (int e = 0; e < 8; ++e) acc[e] += bf2f(v[e]);
        }
        float s = 1.0f + epsArr[layer];
        bf16x8 hv = *(const bf16x8*)(tab + (size_t)node * 16 + lane2 * 8);
#pragma unroll
        for (int e = 0; e < 8; ++e) o[e] = f2bf(fmaf(s, bf2f(hv[e]), acc[e]));
    } else {
        o = (bf16x8)(short)0;
    }
    __builtin_nontemporal_store(o, (bf16x8*)(z + (size_t)slice * SLAB_Z + (size_t)node * 16 + lane2 * 8));
}

// ---------------- fused MLP + LN(+skipLN+ReLU) + residual ----------------
// LDS map: [0,32K) W1 then (restaged) W2; [32K,48K) hid; [48K,48K+3K) param vectors.
// Z (8-sliced, nt-loads) in, H (f32 rows) out, HB (8-sliced bf16, nt-stores) out.
template <bool LAST>
__global__ __launch_bounds__(256, 2) void mlp_kernel(const short* __restrict__ Z,
                                                     const short* __restrict__ Wt1,
                                                     const float* __restrict__ B1,
                                                     const short* __restrict__ Wt2,
                                                     const float* __restrict__ B2,
                                                     const float* __restrict__ G1,
                                                     const float* __restrict__ Bt1,
                                                     const float* __restrict__ G2,
                                                     const float* __restrict__ Bt2,
                                                     const float* __restrict__ RS,
                                                     float* __restrict__ H,
                                                     short* __restrict__ HB) {
    __shared__ __align__(16) char lds[49152 + 3072];
    const int t = threadIdx.x;
    const int wave = t >> 6, lane = t & 63;
    const int r = lane & 15, kq = lane >> 4;
    const int lrow = wave * 16 + r;
    const int row = blockIdx.x * 64 + lrow;
    const int swzr = (r & 7) << 4;
    const int swzl = (lrow & 7) << 4;
    const int fcol = kq * 16;
    const int khalf = kq >> 1, koff = (kq & 1) * 8;

    // ---- prefetch Z fragments (slab 2k+khalf holds feats [32k+16*khalf, +16)) ----
    bf16x8 zb0 = __builtin_nontemporal_load((const bf16x8*)(Z + (size_t)(0 + khalf) * SLAB_Z + (size_t)row * 16 + koff));
    bf16x8 zb1 = __builtin_nontemporal_load((const bf16x8*)(Z + (size_t)(2 + khalf) * SLAB_Z + (size_t)row * 16 + koff));
    bf16x8 zb2 = __builtin_nontemporal_load((const bf16x8*)(Z + (size_t)(4 + khalf) * SLAB_Z + (size_t)row * 16 + koff));
    bf16x8 zb3 = __builtin_nontemporal_load((const bf16x8*)(Z + (size_t)(6 + khalf) * SLAB_Z + (size_t)row * 16 + koff));
    __builtin_amdgcn_sched_barrier(0);

    // ---- stage W1 (32KB) + param vectors; issue W2 loads (held in regs) ----
    bf16x8 g2[8];
    {
        bf16x8 g1[8];
#pragma unroll
        for (int i = 0; i < 8; ++i) g1[i] = *(const bf16x8*)(Wt1 + i * 2048 + t * 8);
#pragma unroll
        for (int i = 0; i < 8; ++i) g2[i] = *(const bf16x8*)(Wt2 + i * 2048 + t * 8);
        if (t < (LAST ? 128 : 192)) {
            int which = t >> 5, chunk = t & 31;
            const float* vp = (which == 0) ? B1 : (which == 1) ? B2 : (which == 2) ? G1
                            : (which == 3) ? Bt1 : (which == 4) ? G2 : Bt2;
            *(f32x4*)(lds + 49152 + which * 512 + chunk * 16) = *(const f32x4*)(vp + chunk * 4);
        }
#pragma unroll
        for (int i = 0; i < 8; ++i) {
            int b = i * 4096 + t * 16;
            *(bf16x8*)(lds + (b ^ (((b >> 8) & 7) << 4))) = g1[i];
        }
    }
    __syncthreads();

    // ---- GEMM1 (W1 from LDS) + bias + ReLU -> p[] in regs ----
    bf16x4 p[8];
#pragma unroll
    for (int ct = 0; ct < 8; ++ct) {
        int wb = (ct * 16 + r) * 256 + kq * 16;
        f32x4 acc = {0.f, 0.f, 0.f, 0.f};
        acc = __builtin_amdgcn_mfma_f32_16x16x32_bf16(*(const bf16x8*)(lds + ((wb      ) ^ swzr)), zb0, acc, 0, 0, 0);
        acc = __builtin_amdgcn_mfma_f32_16x16x32_bf16(*(const bf16x8*)(lds + ((wb +  64) ^ swzr)), zb1, acc, 0, 0, 0);
        acc = __builtin_amdgcn_mfma_f32_16x16x32_bf16(*(const bf16x8*)(lds + ((wb + 128) ^ swzr)), zb2, acc, 0, 0, 0);
        acc = __builtin_amdgcn_mfma_f32_16x16x32_bf16(*(const bf16x8*)(lds + ((wb + 192) ^ swzr)), zb3, acc, 0, 0, 0);
        f32x4 bias = *(const f32x4*)(lds + 49152 + 0 + ct * 64 + fcol);
        p[ct][0] = f2bf(fmaxf(acc[0] + bias.x, 0.0f));
        p[ct][1] = f2bf(fmaxf(acc[1] + bias.y, 0.0f));
        p[ct][2] = f2bf(fmaxf(acc[2] + bias.z, 0.0f));
        p[ct][3] = f2bf(fmaxf(acc[3] + bias.w, 0.0f));
    }
    __syncthreads();   // all W1 LDS reads complete

    // ---- issue residual loads (latency hides under GEMM2) ----
    f32x4 rsv[8] = {};
    if (row < N_NODES) {
#pragma unroll
        for (int ct = 0; ct < 8; ++ct)
            rsv[ct] = *(const f32x4*)(RS + (size_t)row * D + ct * 16 + kq * 4);
    }
    __builtin_amdgcn_sched_barrier(0);

    // ---- restage W2 into [0,32K) (regs -> LDS), write hid into [32K,48K) ----
#pragma unroll
    for (int i = 0; i < 8; ++i) {
        int b = i * 4096 + t * 16;
        *(bf16x8*)(lds + (b ^ (((b >> 8) & 7) << 4))) = g2[i];
    }
#pragma unroll
    for (int ct = 0; ct < 8; ++ct)
        *(bf16x4*)(lds + 32768 + ((lrow * 256 + ct * 32 + kq * 8) ^ swzl)) = p[ct];
    __syncthreads();

    // ---- hid B-fragments from LDS ----
    bf16x8 hb0 = *(const bf16x8*)(lds + 32768 + ((lrow * 256 +   0 + kq * 16) ^ swzl));
    bf16x8 hb1 = *(const bf16x8*)(lds + 32768 + ((lrow * 256 +  64 + kq * 16) ^ swzl));
    bf16x8 hb2 = *(const bf16x8*)(lds + 32768 + ((lrow * 256 + 128 + kq * 16) ^ swzl));
    bf16x8 hb3 = *(const bf16x8*)(lds + 32768 + ((lrow * 256 + 192 + kq * 16) ^ swzl));

    // ---- GEMM2 (W2 from LDS) + bias ----
    f32x4 o[8];
#pragma unroll
    for (int ct = 0; ct < 8; ++ct) {
        int wb = (ct * 16 + r) * 256 + kq * 16;
        f32x4 acc = {0.f, 0.f, 0.f, 0.f};
        acc = __builtin_amdgcn_mfma_f32_16x16x32_bf16(*(const bf16x8*)(lds + ((wb      ) ^ swzr)), hb0, acc, 0, 0, 0);
        acc = __builtin_amdgcn_mfma_f32_16x16x32_bf16(*(const bf16x8*)(lds + ((wb +  64) ^ swzr)), hb1, acc, 0, 0, 0);
        acc = __builtin_amdgcn_mfma_f32_16x16x32_bf16(*(const bf16x8*)(lds + ((wb + 128) ^ swzr)), hb2, acc, 0, 0, 0);
        acc = __builtin_amdgcn_mfma_f32_16x16x32_bf16(*(const bf16x8*)(lds + ((wb + 192) ^ swzr)), hb3, acc, 0, 0, 0);
        f32x4 bias = *(const f32x4*)(lds + 49152 + 512 + ct * 64 + fcol);
        o[ct] = acc + bias;
    }

    // ---- LayerNorm over the row ----
    float s = 0.f, q = 0.f;
#pragma unroll
    for (int ct = 0; ct < 8; ++ct) {
        s += o[ct].x + o[ct].y + o[ct].z + o[ct].w;
        q += o[ct].x * o[ct].x + o[ct].y * o[ct].y + o[ct].z * o[ct].z + o[ct].w * o[ct].w;
    }
    s += __shfl_xor(s, 16, 64); q += __shfl_xor(q, 16, 64);
    s += __shfl_xor(s, 32, 64); q += __shfl_xor(q, 32, 64);
    float mu = s * (1.0f / D);
    float rstd = rsqrtf(q * (1.0f / D) - mu * mu + 1e-5f);
#pragma unroll
    for (int ct = 0; ct < 8; ++ct) {
        f32x4 g = *(const f32x4*)(lds + 49152 + 1024 + ct * 64 + fcol);
        f32x4 b = *(const f32x4*)(lds + 49152 + 1536 + ct * 64 + fcol);
        o[ct] = (o[ct] - mu) * rstd * g + b;
    }

    if (!LAST) {
        float s2 = 0.f, q2 = 0.f;
#pragma unroll
        for (int ct = 0; ct < 8; ++ct) {
            s2 += o[ct].x + o[ct].y + o[ct].z + o[ct].w;
            q2 += o[ct].x * o[ct].x + o[ct].y * o[ct].y + o[ct].z * o[ct].z + o[ct].w * o[ct].w;
        }
        s2 += __shfl_xor(s2, 16, 64); q2 += __shfl_xor(q2, 16, 64);
        s2 += __shfl_xor(s2, 32, 64); q2 += __shfl_xor(q2, 32, 64);
        float mu2 = s2 * (1.0f / D);
        float rstd2 = rsqrtf(q2 * (1.0f / D) - mu2 * mu2 + 1e-5f);
#pragma unroll
        for (int ct = 0; ct < 8; ++ct) {
            f32x4 g = *(const f32x4*)(lds + 49152 + 2048 + ct * 64 + fcol);
            f32x4 b = *(const f32x4*)(lds + 49152 + 2560 + ct * 64 + fcol);
            f32x4 y = (o[ct] - mu2) * rstd2 * g + b;
            y.x = fmaxf(y.x, 0.f); y.y = fmaxf(y.y, 0.f);
            y.z = fmaxf(y.z, 0.f); y.w = fmaxf(y.w, 0.f);
            o[ct] = y;
        }
    }

    // ---- residual + store (H row-major f32; HB 8-sliced bf16, nt) ----
    if (row < N_NODES) {
#pragma unroll
        for (int ct = 0; ct < 8; ++ct) {
            size_t off = (size_t)row * D + ct * 16 + kq * 4;
            f32x4 hv = rsv[ct] + o[ct];
            *(f32x4*)(H + off) = hv;
            if (!LAST) {
                bf16x4 pb;
                pb[0] = f2bf(hv.x); pb[1] = f2bf(hv.y); pb[2] = f2bf(hv.z); pb[3] = f2bf(hv.w);
                // feature f0 = ct*16 + kq*4 -> slab ct, offset kq*4
                __builtin_nontemporal_store(pb,
                    (bf16x4*)(HB + (size_t)ct * SLAB_HB + (size_t)row * 16 + kq * 4));
            }
        }
    }
}

extern "C" void kernel_launch(void* const* d_in, const int* in_sizes, int n_in,
                              void* d_out, int out_size, void* d_ws, size_t ws_size,
                              hipStream_t stream) {
    const float* x   = (const float*)d_in[0];
    const int*   ei  = (const int*)d_in[1];
    const float* eps = (const float*)d_in[2];
    const float* W1  = (const float*)d_in[3];
    const float* b1  = (const float*)d_in[4];
    const float* W2  = (const float*)d_in[5];
    const float* b2  = (const float*)d_in[6];
    const float* lng = (const float*)d_in[7];
    const float* lnb = (const float*)d_in[8];
    const float* skg = (const float*)d_in[9];
    const float* skb = (const float*)d_in[10];
    float* h = (float*)d_out;

    char* ws = (char*)d_ws;
    short* zbuf = (short*)ws;                         // 8*SLAB_Z*2   = 12,812,288 B
    short* hbb  = (short*)(ws + 12812288);            // 8*SLAB_HB*2  = 12,800,000 B
    short* wt   = (short*)(ws + 25612288);            //    196,608 B
    int*   rs   = (int*)  (ws + 25808896);            //    200,192 B
    int*   deg  = (int*)  (ws + 26009088);            //    200,192 B
    int*   cur  = (int*)  (ws + 26209280);            //    200,192 B
    int*   col  = (int*)  (ws + 26409472);            //  2,560,000 B
    int*   bsum = (int*)  (ws + 28969472);            //      1,024 B

    const int* srcIdx = ei;
    const int* dstIdx = ei + N_EDGES;

    init_kernel<<<(N_NODES * 16 + 255) / 256, 256, 0, stream>>>(x, hbb);
    prepw_kernel<<<(6 * 16384) / 256, 256, 0, stream>>>(W1, W2, wt);

    hipMemsetAsync(deg, 0, 2 * 200192, stream);  // deg + cur contiguous
    hist_kernel<<<(N_EDGES + 255) / 256, 256, 0, stream>>>(dstIdx, deg);
    scan1_kernel<<<SCAN_NB, 256, 0, stream>>>(deg, rs, bsum);
    scan2_kernel<<<1, 256, 0, stream>>>(bsum);
    scan3_kernel<<<SCAN_NB, 256, 0, stream>>>(rs, bsum);
    fill_kernel<<<(N_EDGES + 255) / 256, 256, 0, stream>>>(srcIdx, dstIdx, rs, cur, col);

    for (int l = 0; l < LAYERS; ++l) {
        // grid: 391 chunks x 8 slices; slice = blockIdx&7 = XCD id (round-robin)
        agg_kernel<<<391 * 8, 256, 0, stream>>>(
            hbb, rs, deg, col, eps, l, zbuf);
        const float* rsrc = (l == 0) ? x : h;
        if (l < LAYERS - 1) {
            mlp_kernel<false><<<NPAD / 64, 256, 0, stream>>>(
                zbuf, wt + l * 16384, b1 + l * D, wt + (3 + l) * 16384, b2 + l * D,
                lng + l * D, lnb + l * D, skg + l * D, skb + l * D, rsrc, h, hbb);
        } else {
            mlp_kernel<true><<<NPAD / 64, 256, 0, stream>>>(
                zbuf, wt + l * 16384, b1 + l * D, wt + (3 + l) * 16384, b2 + l * D,
                lng + l * D, lnb + l * D, nullptr, nullptr, rsrc, h, nullptr);
        }
    }
}

// Round 8
// 251.887 us; speedup vs baseline: 1.2074x; 1.2074x over previous
//
#include <hip/hip_runtime.h>
#include <hip/hip_bf16.h>

#define N_NODES 50000
#define N_EDGES 640000
#define D 128
#define NPAD 50048   // 782 * 64
#define LAYERS 3
#define SCAN_NB 196  // ceil(50000/256)

typedef __attribute__((ext_vector_type(4))) float f32x4;
typedef __attribute__((ext_vector_type(8))) short bf16x8;
typedef __attribute__((ext_vector_type(4))) short bf16x4;

static __device__ __forceinline__ short f2bf(float f) {
    union { float f; unsigned u; } x; x.f = f;
    unsigned r = x.u + 0x7fffu + ((x.u >> 16) & 1u);  // RNE
    return (short)(r >> 16);
}
static __device__ __forceinline__ float bf2f(short s) {
    union { unsigned u; float f; } x; x.u = ((unsigned)(unsigned short)s) << 16;
    return x.f;
}

// ---------------- hb = bf16(x), row-major [node][128] ----------------
__global__ void init_kernel(const f32x4* __restrict__ in, bf16x4* __restrict__ hb) {
    int t = blockIdx.x * 256 + threadIdx.x;
    f32x4 v = in[t];
    bf16x4 p; p[0] = f2bf(v.x); p[1] = f2bf(v.y); p[2] = f2bf(v.z); p[3] = f2bf(v.w);
    hb[t] = p;
}

// ---------------- weights: wt[m][c][k] = bf16(W[m][k][c]) ----------------
__global__ void prepw_kernel(const float* __restrict__ W1, const float* __restrict__ W2,
                             short* __restrict__ wt) {
    int t = blockIdx.x * 256 + threadIdx.x;
    if (t >= 6 * 16384) return;
    int m = t >> 14, rem = t & 16383;
    int c = rem >> 7, k = rem & 127;
    const float* src = (m < 3) ? (W1 + m * 16384) : (W2 + (m - 3) * 16384);
    wt[m * 16384 + c * 128 + k] = f2bf(src[k * 128 + c]);
}

// ---------------- CSR build ----------------
__global__ void hist_kernel(const int* __restrict__ dst, int* __restrict__ deg) {
    int e = blockIdx.x * 256 + threadIdx.x;
    if (e < N_EDGES) atomicAdd(&deg[dst[e]], 1);
}

__global__ void scan1_kernel(const int* __restrict__ deg, int* __restrict__ rs,
                             int* __restrict__ bsum) {
    __shared__ int tmp[256];
    int i = blockIdx.x * 256 + threadIdx.x;
    int v = (i < N_NODES) ? deg[i] : 0;
    tmp[threadIdx.x] = v;
    __syncthreads();
    for (int off = 1; off < 256; off <<= 1) {
        int t = (threadIdx.x >= off) ? tmp[threadIdx.x - off] : 0;
        __syncthreads();
        tmp[threadIdx.x] += t;
        __syncthreads();
    }
    if (i < N_NODES) rs[i] = tmp[threadIdx.x] - v;  // exclusive
    if (threadIdx.x == 255) bsum[blockIdx.x] = tmp[255];
}

__global__ void scan2_kernel(int* __restrict__ bsum) {
    __shared__ int tmp[256];
    int v = (threadIdx.x < SCAN_NB) ? bsum[threadIdx.x] : 0;
    tmp[threadIdx.x] = v;
    __syncthreads();
    for (int off = 1; off < 256; off <<= 1) {
        int t = (threadIdx.x >= off) ? tmp[threadIdx.x - off] : 0;
        __syncthreads();
        tmp[threadIdx.x] += t;
        __syncthreads();
    }
    if (threadIdx.x < SCAN_NB) bsum[threadIdx.x] = tmp[threadIdx.x] - v;  // exclusive
}

__global__ void scan3_kernel(int* __restrict__ rs, const int* __restrict__ bsum) {
    int i = blockIdx.x * 256 + threadIdx.x;
    if (i < N_NODES) rs[i] += bsum[blockIdx.x];
}

__global__ void fill_kernel(const int* __restrict__ src, const int* __restrict__ dst,
                            const int* __restrict__ rs, int* __restrict__ cursor,
                            int* __restrict__ col) {
    int e = blockIdx.x * 256 + threadIdx.x;
    if (e >= N_EDGES) return;
    int d = dst[e];
    int p = atomicAdd(&cursor[d], 1);
    col[rs[d] + p] = src[e];
}

// ---------------- fused aggregate + GIN prep: z = bf16((1+eps)*hb + sum hb[src]) --------
// 16 lanes/node. Cooperative col loads: lane l loads cp[base+l] (1 instr / 16 edges),
// distributed via __shfl(width=16). Gathers: fully-unrolled 16-deep masked batch
// (j<n is uniform per 16-lane group -> cheap predication, loads stay pipelined).
__global__ __launch_bounds__(256) void agg_kernel(const bf16x8* __restrict__ hb,
                                                  const int* __restrict__ rs,
                                                  const int* __restrict__ deg,
                                                  const int* __restrict__ col,
                                                  const float* __restrict__ epsArr, int layer,
                                                  bf16x8* __restrict__ z) {
    int t = blockIdx.x * 256 + threadIdx.x;
    int node = t >> 4, lane = t & 15;
    if (node >= NPAD) return;
    bf16x8 o;
    if (node < N_NODES) {
        float acc[8] = {0.f, 0.f, 0.f, 0.f, 0.f, 0.f, 0.f, 0.f};
        int start = rs[node], dg = deg[node];
        const int* cp = col + start;
        for (int base = 0; base < dg; base += 16) {
            int n = dg - base; n = n < 16 ? n : 16;
            int my = (lane < n) ? cp[base + lane] : 0;
            bf16x8 v[16];
#pragma unroll
            for (int j = 0; j < 16; ++j) {
                if (j < n) {
                    int idx = __shfl(my, j, 16);
                    v[j] = hb[(size_t)idx * 16 + lane];
                }
            }
#pragma unroll
            for (int j = 0; j < 16; ++j) {
                if (j < n) {
#pragma unroll
                    for (int e = 0; e < 8; ++e) acc[e] += bf2f(v[j][e]);
                }
            }
        }
        float s = 1.0f + epsArr[layer];
        bf16x8 hv = hb[(size_t)node * 16 + lane];
#pragma unroll
        for (int e = 0; e < 8; ++e) o[e] = f2bf(fmaf(s, bf2f(hv[e]), acc[e]));
    } else {
        o = (bf16x8)(short)0;
    }
    z[(size_t)node * 16 + lane] = o;
}

// ---------------- fused MLP + LN(+skipLN+ReLU) + residual ----------------
// LDS map: [0,32K) W1 then (restaged) W2; [32K,48K) hid; [48K,48K+3K) param vectors.
template <bool LAST>
__global__ __launch_bounds__(256, 2) void mlp_kernel(const short* __restrict__ Z,
                                                     const short* __restrict__ Wt1,
                                                     const float* __restrict__ B1,
                                                     const short* __restrict__ Wt2,
                                                     const float* __restrict__ B2,
                                                     const float* __restrict__ G1,
                                                     const float* __restrict__ Bt1,
                                                     const float* __restrict__ G2,
                                                     const float* __restrict__ Bt2,
                                                     const float* __restrict__ RS,
                                                     float* __restrict__ H,
                                                     short* __restrict__ HB) {
    __shared__ __align__(16) char lds[49152 + 3072];
    const int t = threadIdx.x;
    const int wave = t >> 6, lane = t & 63;
    const int r = lane & 15, kq = lane >> 4;
    const int lrow = wave * 16 + r;
    const int row = blockIdx.x * 64 + lrow;
    const int swzr = (r & 7) << 4;
    const int swzl = (lrow & 7) << 4;
    const int fcol = kq * 16;

    // ---- prefetch Z fragments (needed first) ----
    const short* Zr = Z + (size_t)row * D + kq * 8;
    bf16x8 zb0 = *(const bf16x8*)(Zr);
    bf16x8 zb1 = *(const bf16x8*)(Zr + 32);
    bf16x8 zb2 = *(const bf16x8*)(Zr + 64);
    bf16x8 zb3 = *(const bf16x8*)(Zr + 96);
    __builtin_amdgcn_sched_barrier(0);

    // ---- stage W1 (32KB) + param vectors; issue W2 loads (held in regs) ----
    bf16x8 g2[8];
    {
        bf16x8 g1[8];
#pragma unroll
        for (int i = 0; i < 8; ++i) g1[i] = *(const bf16x8*)(Wt1 + i * 2048 + t * 8);
#pragma unroll
        for (int i = 0; i < 8; ++i) g2[i] = *(const bf16x8*)(Wt2 + i * 2048 + t * 8);
        if (t < (LAST ? 128 : 192)) {
            int which = t >> 5, chunk = t & 31;
            const float* vp = (which == 0) ? B1 : (which == 1) ? B2 : (which == 2) ? G1
                            : (which == 3) ? Bt1 : (which == 4) ? G2 : Bt2;
            *(f32x4*)(lds + 49152 + which * 512 + chunk * 16) = *(const f32x4*)(vp + chunk * 4);
        }
#pragma unroll
        for (int i = 0; i < 8; ++i) {
            int b = i * 4096 + t * 16;
            *(bf16x8*)(lds + (b ^ (((b >> 8) & 7) << 4))) = g1[i];
        }
    }
    __syncthreads();

    // ---- GEMM1 (W1 from LDS) + bias + ReLU -> p[] in regs ----
    bf16x4 p[8];
#pragma unroll
    for (int ct = 0; ct < 8; ++ct) {
        int wb = (ct * 16 + r) * 256 + kq * 16;
        f32x4 acc = {0.f, 0.f, 0.f, 0.f};
        acc = __builtin_amdgcn_mfma_f32_16x16x32_bf16(*(const bf16x8*)(lds + ((wb      ) ^ swzr)), zb0, acc, 0, 0, 0);
        acc = __builtin_amdgcn_mfma_f32_16x16x32_bf16(*(const bf16x8*)(lds + ((wb +  64) ^ swzr)), zb1, acc, 0, 0, 0);
        acc = __builtin_amdgcn_mfma_f32_16x16x32_bf16(*(const bf16x8*)(lds + ((wb + 128) ^ swzr)), zb2, acc, 0, 0, 0);
        acc = __builtin_amdgcn_mfma_f32_16x16x32_bf16(*(const bf16x8*)(lds + ((wb + 192) ^ swzr)), zb3, acc, 0, 0, 0);
        f32x4 bias = *(const f32x4*)(lds + 49152 + 0 + ct * 64 + fcol);
        p[ct][0] = f2bf(fmaxf(acc[0] + bias.x, 0.0f));
        p[ct][1] = f2bf(fmaxf(acc[1] + bias.y, 0.0f));
        p[ct][2] = f2bf(fmaxf(acc[2] + bias.z, 0.0f));
        p[ct][3] = f2bf(fmaxf(acc[3] + bias.w, 0.0f));
    }
    __syncthreads();   // all W1 LDS reads complete

    // ---- issue residual loads (latency hides under GEMM2) ----
    f32x4 rsv[8] = {};
    if (row < N_NODES) {
#pragma unroll
        for (int ct = 0; ct < 8; ++ct)
            rsv[ct] = *(const f32x4*)(RS + (size_t)row * D + ct * 16 + kq * 4);
    }
    __builtin_amdgcn_sched_barrier(0);

    // ---- restage W2 into [0,32K) (regs -> LDS), write hid into [32K,48K) ----
#pragma unroll
    for (int i = 0; i < 8; ++i) {
        int b = i * 4096 + t * 16;
        *(bf16x8*)(lds + (b ^ (((b >> 8) & 7) << 4))) = g2[i];
    }
#pragma unroll
    for (int ct = 0; ct < 8; ++ct)
        *(bf16x4*)(lds + 32768 + ((lrow * 256 + ct * 32 + kq * 8) ^ swzl)) = p[ct];
    __syncthreads();

    // ---- hid B-fragments from LDS ----
    bf16x8 hb0 = *(const bf16x8*)(lds + 32768 + ((lrow * 256 +   0 + kq * 16) ^ swzl));
    bf16x8 hb1 = *(const bf16x8*)(lds + 32768 + ((lrow * 256 +  64 + kq * 16) ^ swzl));
    bf16x8 hb2 = *(const bf16x8*)(lds + 32768 + ((lrow * 256 + 128 + kq * 16) ^ swzl));
    bf16x8 hb3 = *(const bf16x8*)(lds + 32768 + ((lrow * 256 + 192 + kq * 16) ^ swzl));

    // ---- GEMM2 (W2 from LDS) + bias ----
    f32x4 o[8];
#pragma unroll
    for (int ct = 0; ct < 8; ++ct) {
        int wb = (ct * 16 + r) * 256 + kq * 16;
        f32x4 acc = {0.f, 0.f, 0.f, 0.f};
        acc = __builtin_amdgcn_mfma_f32_16x16x32_bf16(*(const bf16x8*)(lds + ((wb      ) ^ swzr)), hb0, acc, 0, 0, 0);
        acc = __builtin_amdgcn_mfma_f32_16x16x32_bf16(*(const bf16x8*)(lds + ((wb +  64) ^ swzr)), hb1, acc, 0, 0, 0);
        acc = __builtin_amdgcn_mfma_f32_16x16x32_bf16(*(const bf16x8*)(lds + ((wb + 128) ^ swzr)), hb2, acc, 0, 0, 0);
        acc = __builtin_amdgcn_mfma_f32_16x16x32_bf16(*(const bf16x8*)(lds + ((wb + 192) ^ swzr)), hb3, acc, 0, 0, 0);
        f32x4 bias = *(const f32x4*)(lds + 49152 + 512 + ct * 64 + fcol);
        o[ct] = acc + bias;
    }

    // ---- LayerNorm over the row ----
    float s = 0.f, q = 0.f;
#pragma unroll
    for (int ct = 0; ct < 8; ++ct) {
        s += o[ct].x + o[ct].y + o[ct].z + o[ct].w;
        q += o[ct].x * o[ct].x + o[ct].y * o[ct].y + o[ct].z * o[ct].z + o[ct].w * o[ct].w;
    }
    s += __shfl_xor(s, 16, 64); q += __shfl_xor(q, 16, 64);
    s += __shfl_xor(s, 32, 64); q += __shfl_xor(q, 32, 64);
    float mu = s * (1.0f / D);
    float rstd = rsqrtf(q * (1.0f / D) - mu * mu + 1e-5f);
#pragma unroll
    for (int ct = 0; ct < 8; ++ct) {
        f32x4 g = *(const f32x4*)(lds + 49152 + 1024 + ct * 64 + fcol);
        f32x4 b = *(const f32x4*)(lds + 49152 + 1536 + ct * 64 + fcol);
        o[ct] = (o[ct] - mu) * rstd * g + b;
    }

    if (!LAST) {
        float s2 = 0.f, q2 = 0.f;
#pragma unroll
        for (int ct = 0; ct < 8; ++ct) {
            s2 += o[ct].x + o[ct].y + o[ct].z + o[ct].w;
            q2 += o[ct].x * o[ct].x + o[ct].y * o[ct].y + o[ct].z * o[ct].z + o[ct].w * o[ct].w;
        }
        s2 += __shfl_xor(s2, 16, 64); q2 += __shfl_xor(q2, 16, 64);
        s2 += __shfl_xor(s2, 32, 64); q2 += __shfl_xor(q2, 32, 64);
        float mu2 = s2 * (1.0f / D);
        float rstd2 = rsqrtf(q2 * (1.0f / D) - mu2 * mu2 + 1e-5f);
#pragma unroll
        for (int ct = 0; ct < 8; ++ct) {
            f32x4 g = *(const f32x4*)(lds + 49152 + 2048 + ct * 64 + fcol);
            f32x4 b = *(const f32x4*)(lds + 49152 + 2560 + ct * 64 + fcol);
            f32x4 y = (o[ct] - mu2) * rstd2 * g + b;
            y.x = fmaxf(y.x, 0.f); y.y = fmaxf(y.y, 0.f);
            y.z = fmaxf(y.z, 0.f); y.w = fmaxf(y.w, 0.f);
            o[ct] = y;
        }
    }

    // ---- residual + store ----
    if (row < N_NODES) {
#pragma unroll
        for (int ct = 0; ct < 8; ++ct) {
            size_t off = (size_t)row * D + ct * 16 + kq * 4;
            f32x4 hv = rsv[ct] + o[ct];
            *(f32x4*)(H + off) = hv;
            if (!LAST) {
                bf16x4 pb;
                pb[0] = f2bf(hv.x); pb[1] = f2bf(hv.y); pb[2] = f2bf(hv.z); pb[3] = f2bf(hv.w);
                *(bf16x4*)(HB + off) = pb;
            }
        }
    }
}

extern "C" void kernel_launch(void* const* d_in, const int* in_sizes, int n_in,
                              void* d_out, int out_size, void* d_ws, size_t ws_size,
                              hipStream_t stream) {
    const float* x   = (const float*)d_in[0];
    const int*   ei  = (const int*)d_in[1];
    const float* eps = (const float*)d_in[2];
    const float* W1  = (const float*)d_in[3];
    const float* b1  = (const float*)d_in[4];
    const float* W2  = (const float*)d_in[5];
    const float* b2  = (const float*)d_in[6];
    const float* lng = (const float*)d_in[7];
    const float* lnb = (const float*)d_in[8];
    const float* skg = (const float*)d_in[9];
    const float* skb = (const float*)d_in[10];
    float* h = (float*)d_out;

    char* ws = (char*)d_ws;
    short* zbuf = (short*)ws;                         // 12,812,288 B
    short* hbb  = (short*)(ws + 12812288);            // 12,812,288 B
    short* wt   = (short*)(ws + 25624576);            //    196,608 B
    int*   rs   = (int*)  (ws + 25821184);            //    200,192 B
    int*   deg  = (int*)  (ws + 26021376);            //    200,192 B
    int*   cur  = (int*)  (ws + 26221568);            //    200,192 B
    int*   col  = (int*)  (ws + 26421760);            //  2,560,000 B
    int*   bsum = (int*)  (ws + 28981760);            //      1,024 B

    const int* srcIdx = ei;
    const int* dstIdx = ei + N_EDGES;

    init_kernel<<<(N_NODES * 32) / 256, 256, 0, stream>>>((const f32x4*)x, (bf16x4*)hbb);
    prepw_kernel<<<(6 * 16384) / 256, 256, 0, stream>>>(W1, W2, wt);

    hipMemsetAsync(deg, 0, 2 * 200192, stream);  // deg + cur contiguous
    hist_kernel<<<(N_EDGES + 255) / 256, 256, 0, stream>>>(dstIdx, deg);
    scan1_kernel<<<SCAN_NB, 256, 0, stream>>>(deg, rs, bsum);
    scan2_kernel<<<1, 256, 0, stream>>>(bsum);
    scan3_kernel<<<SCAN_NB, 256, 0, stream>>>(rs, bsum);
    fill_kernel<<<(N_EDGES + 255) / 256, 256, 0, stream>>>(srcIdx, dstIdx, rs, cur, col);

    for (int l = 0; l < LAYERS; ++l) {
        agg_kernel<<<NPAD / 16, 256, 0, stream>>>(
            (const bf16x8*)hbb, rs, deg, col, eps, l, (bf16x8*)zbuf);
        const float* rsrc = (l == 0) ? x : h;
        if (l < LAYERS - 1) {
            mlp_kernel<false><<<NPAD / 64, 256, 0, stream>>>(
                zbuf, wt + l * 16384, b1 + l * D, wt + (3 + l) * 16384, b2 + l * D,
                lng + l * D, lnb + l * D, skg + l * D, skb + l * D, rsrc, h, hbb);
        } else {
            mlp_kernel<true><<<NPAD / 64, 256, 0, stream>>>(
                zbuf, wt + l * 16384, b1 + l * D, wt + (3 + l) * 16384, b2 + l * D,
                lng + l * D, lnb + l * D, nullptr, nullptr, rsrc, h, nullptr);
        }
    }
}

// Round 10
// 235.739 us; speedup vs baseline: 1.2901x; 1.0685x over previous
//
#include <hip/hip_runtime.h>
#include <hip/hip_bf16.h>

#define N_NODES 50000
#define N_EDGES 640000
#define D 128
#define NPAD 50048   // 782 * 64
#define LAYERS 3
#define SCAN_NB 196  // ceil(50000/256)

typedef __attribute__((ext_vector_type(4))) float f32x4;
typedef __attribute__((ext_vector_type(8))) short bf16x8;
typedef __attribute__((ext_vector_type(4))) short bf16x4;

static __device__ __forceinline__ short f2bf(float f) {
    union { float f; unsigned u; } x; x.f = f;
    unsigned r = x.u + 0x7fffu + ((x.u >> 16) & 1u);  // RNE
    return (short)(r >> 16);
}
static __device__ __forceinline__ float bf2f(short s) {
    union { unsigned u; float f; } x; x.u = ((unsigned)(unsigned short)s) << 16;
    return x.f;
}

// ---------------- hb = bf16(x), row-major [node][128] ----------------
__global__ void init_kernel(const f32x4* __restrict__ in, bf16x4* __restrict__ hb) {
    int t = blockIdx.x * 256 + threadIdx.x;
    f32x4 v = in[t];
    bf16x4 p; p[0] = f2bf(v.x); p[1] = f2bf(v.y); p[2] = f2bf(v.z); p[3] = f2bf(v.w);
    hb[t] = p;
}

// ---------------- weights: wt[m][c][k] = bf16(W[m][k][c]) ----------------
__global__ void prepw_kernel(const float* __restrict__ W1, const float* __restrict__ W2,
                             short* __restrict__ wt) {
    int t = blockIdx.x * 256 + threadIdx.x;
    if (t >= 6 * 16384) return;
    int m = t >> 14, rem = t & 16383;
    int c = rem >> 7, k = rem & 127;
    const float* src = (m < 3) ? (W1 + m * 16384) : (W2 + (m - 3) * 16384);
    wt[m * 16384 + c * 128 + k] = f2bf(src[k * 128 + c]);
}

// ---------------- CSR build ----------------
__global__ void hist_kernel(const int* __restrict__ dst, int* __restrict__ deg) {
    int e = blockIdx.x * 256 + threadIdx.x;
    if (e < N_EDGES) atomicAdd(&deg[dst[e]], 1);
}

__global__ void scan1_kernel(const int* __restrict__ deg, int* __restrict__ rs,
                             int* __restrict__ bsum) {
    __shared__ int tmp[256];
    int i = blockIdx.x * 256 + threadIdx.x;
    int v = (i < N_NODES) ? deg[i] : 0;
    tmp[threadIdx.x] = v;
    __syncthreads();
    for (int off = 1; off < 256; off <<= 1) {
        int t = (threadIdx.x >= off) ? tmp[threadIdx.x - off] : 0;
        __syncthreads();
        tmp[threadIdx.x] += t;
        __syncthreads();
    }
    if (i < N_NODES) rs[i] = tmp[threadIdx.x] - v;  // exclusive
    if (threadIdx.x == 255) bsum[blockIdx.x] = tmp[255];
}

__global__ void scan2_kernel(int* __restrict__ bsum) {
    __shared__ int tmp[256];
    int v = (threadIdx.x < SCAN_NB) ? bsum[threadIdx.x] : 0;
    tmp[threadIdx.x] = v;
    __syncthreads();
    for (int off = 1; off < 256; off <<= 1) {
        int t = (threadIdx.x >= off) ? tmp[threadIdx.x - off] : 0;
        __syncthreads();
        tmp[threadIdx.x] += t;
        __syncthreads();
    }
    if (threadIdx.x < SCAN_NB) bsum[threadIdx.x] = tmp[threadIdx.x] - v;  // exclusive
}

__global__ void scan3_kernel(int* __restrict__ rs, const int* __restrict__ bsum) {
    int i = blockIdx.x * 256 + threadIdx.x;
    if (i < N_NODES) rs[i] += bsum[blockIdx.x];
}

__global__ void fill_kernel(const int* __restrict__ src, const int* __restrict__ dst,
                            const int* __restrict__ rs, int* __restrict__ cursor,
                            int* __restrict__ col) {
    int e = blockIdx.x * 256 + threadIdx.x;
    if (e >= N_EDGES) return;
    int d = dst[e];
    int p = atomicAdd(&cursor[d], 1);
    col[rs[d] + p] = src[e];
}

// ============ FUSED layer kernel: gather+GIN-prep + MLP + LN(+skipLN+ReLU) + residual ============
// HBin/HBout are DISTINCT buffers (ping-pong) -> no cross-block RAW race (R9 bug).
// Gather: 4 threads/node, 32 feats (64B) each; latency overlaps other blocks' MFMA phases.
// LDS map: [0,32K) W1 then (restaged) W2; [32K,48K) z then hid; [48K,+3K) param vectors.
template <bool LAST>
__global__ __launch_bounds__(256, 2) void fused_kernel(const short* __restrict__ HBin,
                                                       const int* __restrict__ rs,
                                                       const int* __restrict__ deg,
                                                       const int* __restrict__ col,
                                                       const float* __restrict__ epsArr, int layer,
                                                       const short* __restrict__ Wt1,
                                                       const float* __restrict__ B1,
                                                       const short* __restrict__ Wt2,
                                                       const float* __restrict__ B2,
                                                       const float* __restrict__ G1,
                                                       const float* __restrict__ Bt1,
                                                       const float* __restrict__ G2,
                                                       const float* __restrict__ Bt2,
                                                       const float* __restrict__ RS,
                                                       float* __restrict__ H,
                                                       short* __restrict__ HBout) {
    __shared__ __align__(16) char lds[49152 + 3072];
    const int t = threadIdx.x;
    const int wave = t >> 6, lane = t & 63;
    const int r = lane & 15, kq = lane >> 4;
    const int lrow = wave * 16 + r;
    const int row = blockIdx.x * 64 + lrow;
    const int swzr = (r & 7) << 4;
    const int swzl = (lrow & 7) << 4;
    const int fcol = kq * 16;
    const int g = t >> 2, q = t & 3;               // gather role: local row g, quarter q
    const int gnode = blockIdx.x * 64 + g;
    const int gswz = (g & 7) << 4;

    // ---- issue W1 + W2 loads (latency hides under gather compute) ----
    bf16x8 g1[8], g2[8];
#pragma unroll
    for (int i = 0; i < 8; ++i) g1[i] = *(const bf16x8*)(Wt1 + i * 2048 + t * 8);
#pragma unroll
    for (int i = 0; i < 8; ++i) g2[i] = *(const bf16x8*)(Wt2 + i * 2048 + t * 8);
    __builtin_amdgcn_sched_barrier(0);   // pin the W loads before the gather loop

    // ---- gather phase: acc = sum_{nbr} hb[nbr][q*32..+32], then (1+eps)*self ----
    float acc[32];
#pragma unroll
    for (int i = 0; i < 32; ++i) acc[i] = 0.f;
    if (gnode < N_NODES) {
        int start = rs[gnode], dg = deg[gnode];
        const int* cp = col + start;
        const short* tab = HBin + q * 32;
        int e = 0;
        for (; e + 2 <= dg; e += 2) {
            const short* r0 = tab + (size_t)cp[e] * 128;
            const short* r1 = tab + (size_t)cp[e + 1] * 128;
            bf16x8 a0 = *(const bf16x8*)(r0);
            bf16x8 a1 = *(const bf16x8*)(r0 + 8);
            bf16x8 a2 = *(const bf16x8*)(r0 + 16);
            bf16x8 a3 = *(const bf16x8*)(r0 + 24);
            bf16x8 b0 = *(const bf16x8*)(r1);
            bf16x8 b1 = *(const bf16x8*)(r1 + 8);
            bf16x8 b2 = *(const bf16x8*)(r1 + 16);
            bf16x8 b3 = *(const bf16x8*)(r1 + 24);
#pragma unroll
            for (int j = 0; j < 8; ++j) {
                acc[j]      += bf2f(a0[j]) + bf2f(b0[j]);
                acc[8 + j]  += bf2f(a1[j]) + bf2f(b1[j]);
                acc[16 + j] += bf2f(a2[j]) + bf2f(b2[j]);
                acc[24 + j] += bf2f(a3[j]) + bf2f(b3[j]);
            }
        }
        if (e < dg) {
            const short* r0 = tab + (size_t)cp[e] * 128;
            bf16x8 a0 = *(const bf16x8*)(r0);
            bf16x8 a1 = *(const bf16x8*)(r0 + 8);
            bf16x8 a2 = *(const bf16x8*)(r0 + 16);
            bf16x8 a3 = *(const bf16x8*)(r0 + 24);
#pragma unroll
            for (int j = 0; j < 8; ++j) {
                acc[j]      += bf2f(a0[j]);
                acc[8 + j]  += bf2f(a1[j]);
                acc[16 + j] += bf2f(a2[j]);
                acc[24 + j] += bf2f(a3[j]);
            }
        }
        float s = 1.0f + epsArr[layer];
        const short* hs = tab + (size_t)gnode * 128;
        bf16x8 h0 = *(const bf16x8*)(hs);
        bf16x8 h1 = *(const bf16x8*)(hs + 8);
        bf16x8 h2 = *(const bf16x8*)(hs + 16);
        bf16x8 h3 = *(const bf16x8*)(hs + 24);
#pragma unroll
        for (int j = 0; j < 8; ++j) {
            acc[j]      = fmaf(s, bf2f(h0[j]), acc[j]);
            acc[8 + j]  = fmaf(s, bf2f(h1[j]), acc[8 + j]);
            acc[16 + j] = fmaf(s, bf2f(h2[j]), acc[16 + j]);
            acc[24 + j] = fmaf(s, bf2f(h3[j]), acc[24 + j]);
        }
    }
    // pack z quarter (feats q*32..+32) to bf16
    bf16x8 zp[4];
#pragma unroll
    for (int i = 0; i < 4; ++i) {
#pragma unroll
        for (int j = 0; j < 8; ++j) zp[i][j] = f2bf(acc[i * 8 + j]);
    }

    // ---- param vector staging ----
    if (t < (LAST ? 128 : 192)) {
        int which = t >> 5, chunk = t & 31;
        const float* vp = (which == 0) ? B1 : (which == 1) ? B2 : (which == 2) ? G1
                        : (which == 3) ? Bt1 : (which == 4) ? G2 : Bt2;
        *(f32x4*)(lds + 49152 + which * 512 + chunk * 16) = *(const f32x4*)(vp + chunk * 4);
    }
    // ---- stage W1 into [0,32K) and z into [32K,48K) (both swizzled) ----
#pragma unroll
    for (int i = 0; i < 8; ++i) {
        int b = i * 4096 + t * 16;
        *(bf16x8*)(lds + (b ^ (((b >> 8) & 7) << 4))) = g1[i];
    }
#pragma unroll
    for (int i = 0; i < 4; ++i)
        *(bf16x8*)(lds + 32768 + ((g * 256 + q * 64 + i * 16) ^ gswz)) = zp[i];
    __syncthreads();

    // ---- z B-fragments from LDS; issue residual loads (hide under GEMM1) ----
    bf16x8 zb0 = *(const bf16x8*)(lds + 32768 + ((lrow * 256 +   0 + kq * 16) ^ swzl));
    bf16x8 zb1 = *(const bf16x8*)(lds + 32768 + ((lrow * 256 +  64 + kq * 16) ^ swzl));
    bf16x8 zb2 = *(const bf16x8*)(lds + 32768 + ((lrow * 256 + 128 + kq * 16) ^ swzl));
    bf16x8 zb3 = *(const bf16x8*)(lds + 32768 + ((lrow * 256 + 192 + kq * 16) ^ swzl));
    f32x4 rsv[8] = {};
    if (row < N_NODES) {
#pragma unroll
        for (int ct = 0; ct < 8; ++ct)
            rsv[ct] = *(const f32x4*)(RS + (size_t)row * D + ct * 16 + kq * 4);
    }

    // ---- GEMM1 (W1 from LDS) + bias + ReLU -> p[] ----
    bf16x4 p[8];
#pragma unroll
    for (int ct = 0; ct < 8; ++ct) {
        int wb = (ct * 16 + r) * 256 + kq * 16;
        f32x4 a = {0.f, 0.f, 0.f, 0.f};
        a = __builtin_amdgcn_mfma_f32_16x16x32_bf16(*(const bf16x8*)(lds + ((wb      ) ^ swzr)), zb0, a, 0, 0, 0);
        a = __builtin_amdgcn_mfma_f32_16x16x32_bf16(*(const bf16x8*)(lds + ((wb +  64) ^ swzr)), zb1, a, 0, 0, 0);
        a = __builtin_amdgcn_mfma_f32_16x16x32_bf16(*(const bf16x8*)(lds + ((wb + 128) ^ swzr)), zb2, a, 0, 0, 0);
        a = __builtin_amdgcn_mfma_f32_16x16x32_bf16(*(const bf16x8*)(lds + ((wb + 192) ^ swzr)), zb3, a, 0, 0, 0);
        f32x4 bias = *(const f32x4*)(lds + 49152 + 0 + ct * 64 + fcol);
        p[ct][0] = f2bf(fmaxf(a[0] + bias.x, 0.0f));
        p[ct][1] = f2bf(fmaxf(a[1] + bias.y, 0.0f));
        p[ct][2] = f2bf(fmaxf(a[2] + bias.z, 0.0f));
        p[ct][3] = f2bf(fmaxf(a[3] + bias.w, 0.0f));
    }
    __syncthreads();   // W1-region and z-region reads complete

    // ---- restage W2 into [0,32K); write hid into [32K,48K) ----
#pragma unroll
    for (int i = 0; i < 8; ++i) {
        int b = i * 4096 + t * 16;
        *(bf16x8*)(lds + (b ^ (((b >> 8) & 7) << 4))) = g2[i];
    }
#pragma unroll
    for (int ct = 0; ct < 8; ++ct)
        *(bf16x4*)(lds + 32768 + ((lrow * 256 + ct * 32 + kq * 8) ^ swzl)) = p[ct];
    __syncthreads();

    // ---- hid B-fragments ----
    bf16x8 hb0 = *(const bf16x8*)(lds + 32768 + ((lrow * 256 +   0 + kq * 16) ^ swzl));
    bf16x8 hb1 = *(const bf16x8*)(lds + 32768 + ((lrow * 256 +  64 + kq * 16) ^ swzl));
    bf16x8 hb2 = *(const bf16x8*)(lds + 32768 + ((lrow * 256 + 128 + kq * 16) ^ swzl));
    bf16x8 hb3 = *(const bf16x8*)(lds + 32768 + ((lrow * 256 + 192 + kq * 16) ^ swzl));

    // ---- GEMM2 (W2 from LDS) + bias ----
    f32x4 o[8];
#pragma unroll
    for (int ct = 0; ct < 8; ++ct) {
        int wb = (ct * 16 + r) * 256 + kq * 16;
        f32x4 a = {0.f, 0.f, 0.f, 0.f};
        a = __builtin_amdgcn_mfma_f32_16x16x32_bf16(*(const bf16x8*)(lds + ((wb      ) ^ swzr)), hb0, a, 0, 0, 0);
        a = __builtin_amdgcn_mfma_f32_16x16x32_bf16(*(const bf16x8*)(lds + ((wb +  64) ^ swzr)), hb1, a, 0, 0, 0);
        a = __builtin_amdgcn_mfma_f32_16x16x32_bf16(*(const bf16x8*)(lds + ((wb + 128) ^ swzr)), hb2, a, 0, 0, 0);
        a = __builtin_amdgcn_mfma_f32_16x16x32_bf16(*(const bf16x8*)(lds + ((wb + 192) ^ swzr)), hb3, a, 0, 0, 0);
        f32x4 bias = *(const f32x4*)(lds + 49152 + 512 + ct * 64 + fcol);
        o[ct] = a + bias;
    }

    // ---- LayerNorm over the row ----
    float s = 0.f, qq = 0.f;
#pragma unroll
    for (int ct = 0; ct < 8; ++ct) {
        s  += o[ct].x + o[ct].y + o[ct].z + o[ct].w;
        qq += o[ct].x * o[ct].x + o[ct].y * o[ct].y + o[ct].z * o[ct].z + o[ct].w * o[ct].w;
    }
    s += __shfl_xor(s, 16, 64); qq += __shfl_xor(qq, 16, 64);
    s += __shfl_xor(s, 32, 64); qq += __shfl_xor(qq, 32, 64);
    float mu = s * (1.0f / D);
    float rstd = rsqrtf(qq * (1.0f / D) - mu * mu + 1e-5f);
#pragma unroll
    for (int ct = 0; ct < 8; ++ct) {
        f32x4 gv = *(const f32x4*)(lds + 49152 + 1024 + ct * 64 + fcol);
        f32x4 bv = *(const f32x4*)(lds + 49152 + 1536 + ct * 64 + fcol);
        o[ct] = (o[ct] - mu) * rstd * gv + bv;
    }

    if (!LAST) {
        float s2 = 0.f, q2 = 0.f;
#pragma unroll
        for (int ct = 0; ct < 8; ++ct) {
            s2 += o[ct].x + o[ct].y + o[ct].z + o[ct].w;
            q2 += o[ct].x * o[ct].x + o[ct].y * o[ct].y + o[ct].z * o[ct].z + o[ct].w * o[ct].w;
        }
        s2 += __shfl_xor(s2, 16, 64); q2 += __shfl_xor(q2, 16, 64);
        s2 += __shfl_xor(s2, 32, 64); q2 += __shfl_xor(q2, 32, 64);
        float mu2 = s2 * (1.0f / D);
        float rstd2 = rsqrtf(q2 * (1.0f / D) - mu2 * mu2 + 1e-5f);
#pragma unroll
        for (int ct = 0; ct < 8; ++ct) {
            f32x4 gv = *(const f32x4*)(lds + 49152 + 2048 + ct * 64 + fcol);
            f32x4 bv = *(const f32x4*)(lds + 49152 + 2560 + ct * 64 + fcol);
            f32x4 y = (o[ct] - mu2) * rstd2 * gv + bv;
            y.x = fmaxf(y.x, 0.f); y.y = fmaxf(y.y, 0.f);
            y.z = fmaxf(y.z, 0.f); y.w = fmaxf(y.w, 0.f);
            o[ct] = y;
        }
    }

    // ---- residual + store ----
    if (row < N_NODES) {
#pragma unroll
        for (int ct = 0; ct < 8; ++ct) {
            size_t off = (size_t)row * D + ct * 16 + kq * 4;
            f32x4 hv = rsv[ct] + o[ct];
            *(f32x4*)(H + off) = hv;
            if (!LAST) {
                bf16x4 pb;
                pb[0] = f2bf(hv.x); pb[1] = f2bf(hv.y); pb[2] = f2bf(hv.z); pb[3] = f2bf(hv.w);
                *(bf16x4*)(HBout + off) = pb;
            }
        }
    }
}

extern "C" void kernel_launch(void* const* d_in, const int* in_sizes, int n_in,
                              void* d_out, int out_size, void* d_ws, size_t ws_size,
                              hipStream_t stream) {
    const float* x   = (const float*)d_in[0];
    const int*   ei  = (const int*)d_in[1];
    const float* eps = (const float*)d_in[2];
    const float* W1  = (const float*)d_in[3];
    const float* b1  = (const float*)d_in[4];
    const float* W2  = (const float*)d_in[5];
    const float* b2  = (const float*)d_in[6];
    const float* lng = (const float*)d_in[7];
    const float* lnb = (const float*)d_in[8];
    const float* skg = (const float*)d_in[9];
    const float* skb = (const float*)d_in[10];
    float* h = (float*)d_out;

    char* ws = (char*)d_ws;
    short* hb0  = (short*)ws;                         // 12,800,000 B (bf16 [N][128])
    short* hb1  = (short*)(ws + 12800000);            // 12,800,000 B (ping-pong)
    short* wt   = (short*)(ws + 25600000);            //    196,608 B
    int*   rs   = (int*)  (ws + 25796608);            //    200,192 B
    int*   deg  = (int*)  (ws + 25996800);            //    200,192 B
    int*   cur  = (int*)  (ws + 26196992);            //    200,192 B
    int*   col  = (int*)  (ws + 26397184);            //  2,560,000 B
    int*   bsum = (int*)  (ws + 28957184);            //      1,024 B

    const int* srcIdx = ei;
    const int* dstIdx = ei + N_EDGES;

    init_kernel<<<(N_NODES * 32) / 256, 256, 0, stream>>>((const f32x4*)x, (bf16x4*)hb0);
    prepw_kernel<<<(6 * 16384) / 256, 256, 0, stream>>>(W1, W2, wt);

    hipMemsetAsync(deg, 0, 2 * 200192, stream);  // deg + cur contiguous
    hist_kernel<<<(N_EDGES + 255) / 256, 256, 0, stream>>>(dstIdx, deg);
    scan1_kernel<<<SCAN_NB, 256, 0, stream>>>(deg, rs, bsum);
    scan2_kernel<<<1, 256, 0, stream>>>(bsum);
    scan3_kernel<<<SCAN_NB, 256, 0, stream>>>(rs, bsum);
    fill_kernel<<<(N_EDGES + 255) / 256, 256, 0, stream>>>(srcIdx, dstIdx, rs, cur, col);

    short* hbs[2] = {hb0, hb1};
    for (int l = 0; l < LAYERS; ++l) {
        const float* rsrc = (l == 0) ? x : h;
        short* hin  = hbs[l & 1];
        short* hout = hbs[(l + 1) & 1];
        if (l < LAYERS - 1) {
            fused_kernel<false><<<NPAD / 64, 256, 0, stream>>>(
                hin, rs, deg, col, eps, l,
                wt + l * 16384, b1 + l * D, wt + (3 + l) * 16384, b2 + l * D,
                lng + l * D, lnb + l * D, skg + l * D, skb + l * D, rsrc, h, hout);
        } else {
            fused_kernel<true><<<NPAD / 64, 256, 0, stream>>>(
                hin, rs, deg, col, eps, l,
                wt + l * 16384, b1 + l * D, wt + (3 + l) * 16384, b2 + l * D,
                lng + l * D, lnb + l * D, nullptr, nullptr, rsrc, h, nullptr);
        }
    }
}

// Round 11
// 234.461 us; speedup vs baseline: 1.2971x; 1.0055x over previous
//
#include <hip/hip_runtime.h>
#include <hip/hip_bf16.h>

#define N_NODES 50000
#define N_EDGES 640000
#define D 128
#define NPAD 50048   // 782 * 64
#define LAYERS 3
#define SCAN_NB 196  // ceil(50000/256)

typedef __attribute__((ext_vector_type(4))) float f32x4;
typedef __attribute__((ext_vector_type(8))) short bf16x8;
typedef __attribute__((ext_vector_type(4))) short bf16x4;

static __device__ __forceinline__ short f2bf(float f) {
    union { float f; unsigned u; } x; x.f = f;
    unsigned r = x.u + 0x7fffu + ((x.u >> 16) & 1u);  // RNE
    return (short)(r >> 16);
}
static __device__ __forceinline__ float bf2f(short s) {
    union { unsigned u; float f; } x; x.u = ((unsigned)(unsigned short)s) << 16;
    return x.f;
}

// ---------------- hb = bf16(x), row-major [node][128] ----------------
__global__ void init_kernel(const f32x4* __restrict__ in, bf16x4* __restrict__ hb) {
    int t = blockIdx.x * 256 + threadIdx.x;
    f32x4 v = in[t];
    bf16x4 p; p[0] = f2bf(v.x); p[1] = f2bf(v.y); p[2] = f2bf(v.z); p[3] = f2bf(v.w);
    hb[t] = p;
}

// ---------------- weights: wt[m][c][k] = bf16(W[m][k][c]) ----------------
__global__ void prepw_kernel(const float* __restrict__ W1, const float* __restrict__ W2,
                             short* __restrict__ wt) {
    int t = blockIdx.x * 256 + threadIdx.x;
    if (t >= 6 * 16384) return;
    int m = t >> 14, rem = t & 16383;
    int c = rem >> 7, k = rem & 127;
    const float* src = (m < 3) ? (W1 + m * 16384) : (W2 + (m - 3) * 16384);
    wt[m * 16384 + c * 128 + k] = f2bf(src[k * 128 + c]);
}

// ---------------- CSR build ----------------
__global__ void hist_kernel(const int* __restrict__ dst, int* __restrict__ deg) {
    int e = blockIdx.x * 256 + threadIdx.x;
    if (e < N_EDGES) atomicAdd(&deg[dst[e]], 1);
}

__global__ void scan1_kernel(const int* __restrict__ deg, int* __restrict__ rs,
                             int* __restrict__ bsum) {
    __shared__ int tmp[256];
    int i = blockIdx.x * 256 + threadIdx.x;
    int v = (i < N_NODES) ? deg[i] : 0;
    tmp[threadIdx.x] = v;
    __syncthreads();
    for (int off = 1; off < 256; off <<= 1) {
        int t = (threadIdx.x >= off) ? tmp[threadIdx.x - off] : 0;
        __syncthreads();
        tmp[threadIdx.x] += t;
        __syncthreads();
    }
    if (i < N_NODES) rs[i] = tmp[threadIdx.x] - v;  // exclusive
    if (threadIdx.x == 255) bsum[blockIdx.x] = tmp[255];
}

__global__ void scan2_kernel(int* __restrict__ bsum) {
    __shared__ int tmp[256];
    int v = (threadIdx.x < SCAN_NB) ? bsum[threadIdx.x] : 0;
    tmp[threadIdx.x] = v;
    __syncthreads();
    for (int off = 1; off < 256; off <<= 1) {
        int t = (threadIdx.x >= off) ? tmp[threadIdx.x - off] : 0;
        __syncthreads();
        tmp[threadIdx.x] += t;
        __syncthreads();
    }
    if (threadIdx.x < SCAN_NB) bsum[threadIdx.x] = tmp[threadIdx.x] - v;  // exclusive
}

__global__ void scan3_kernel(int* __restrict__ rs, const int* __restrict__ bsum) {
    int i = blockIdx.x * 256 + threadIdx.x;
    if (i < N_NODES) rs[i] += bsum[blockIdx.x];
}

__global__ void fill_kernel(const int* __restrict__ src, const int* __restrict__ dst,
                            const int* __restrict__ rs, int* __restrict__ cursor,
                            int* __restrict__ col) {
    int e = blockIdx.x * 256 + threadIdx.x;
    if (e >= N_EDGES) return;
    int d = dst[e];
    int p = atomicAdd(&cursor[d], 1);
    col[rs[d] + p] = src[e];
}

// ============ FUSED layer kernel: gather+GIN-prep + MLP + LN(+skipLN+ReLU) + residual ============
// HBin/HBout ping-pong (no cross-block RAW race). Gather: 4 threads/node, 32 feats each,
// 4 edges (16 loads) in flight; latency overlaps other blocks' MFMA at 3 blocks/CU.
// LDS map: [0,32K) W1 then (restaged) W2; [32K,48K) z then hid; [48K,+3K) param vectors.
template <bool LAST>
__global__ __launch_bounds__(256, 3) void fused_kernel(const short* __restrict__ HBin,
                                                       const int* __restrict__ rs,
                                                       const int* __restrict__ deg,
                                                       const int* __restrict__ col,
                                                       const float* __restrict__ epsArr, int layer,
                                                       const short* __restrict__ Wt1,
                                                       const float* __restrict__ B1,
                                                       const short* __restrict__ Wt2,
                                                       const float* __restrict__ B2,
                                                       const float* __restrict__ G1,
                                                       const float* __restrict__ Bt1,
                                                       const float* __restrict__ G2,
                                                       const float* __restrict__ Bt2,
                                                       const float* __restrict__ RS,
                                                       float* __restrict__ H,
                                                       short* __restrict__ HBout) {
    __shared__ __align__(16) char lds[49152 + 3072];
    const int t = threadIdx.x;
    const int wave = t >> 6, lane = t & 63;
    const int r = lane & 15, kq = lane >> 4;
    const int lrow = wave * 16 + r;
    const int row = blockIdx.x * 64 + lrow;
    const int swzr = (r & 7) << 4;
    const int swzl = (lrow & 7) << 4;
    const int fcol = kq * 16;
    const int g = t >> 2, q = t & 3;               // gather role: local row g, quarter q
    const int gnode = blockIdx.x * 64 + g;
    const int gswz = (g & 7) << 4;

    // ---- issue W1 + W2 loads (latency hides under gather compute) ----
    bf16x8 g1[8], g2[8];
#pragma unroll
    for (int i = 0; i < 8; ++i) g1[i] = *(const bf16x8*)(Wt1 + i * 2048 + t * 8);
#pragma unroll
    for (int i = 0; i < 8; ++i) g2[i] = *(const bf16x8*)(Wt2 + i * 2048 + t * 8);
    __builtin_amdgcn_sched_barrier(0);   // pin the W loads before the gather loop

    // ---- gather phase: acc = sum_{nbr} hb[nbr][q*32..+32], then (1+eps)*self ----
    float acc[32];
#pragma unroll
    for (int i = 0; i < 32; ++i) acc[i] = 0.f;
    if (gnode < N_NODES) {
        int start = rs[gnode], dg = deg[gnode];
        const int* cp = col + start;
        const short* tab = HBin + q * 32;
        int e = 0;
        // 4 edges = 16 independent 16B loads in flight
        for (; e + 4 <= dg; e += 4) {
            const short* r0 = tab + (size_t)cp[e] * 128;
            const short* r1 = tab + (size_t)cp[e + 1] * 128;
            const short* r2 = tab + (size_t)cp[e + 2] * 128;
            const short* r3 = tab + (size_t)cp[e + 3] * 128;
            bf16x8 a0 = *(const bf16x8*)(r0);
            bf16x8 a1 = *(const bf16x8*)(r0 + 8);
            bf16x8 a2 = *(const bf16x8*)(r0 + 16);
            bf16x8 a3 = *(const bf16x8*)(r0 + 24);
            bf16x8 b0 = *(const bf16x8*)(r1);
            bf16x8 b1 = *(const bf16x8*)(r1 + 8);
            bf16x8 b2 = *(const bf16x8*)(r1 + 16);
            bf16x8 b3 = *(const bf16x8*)(r1 + 24);
            bf16x8 c0 = *(const bf16x8*)(r2);
            bf16x8 c1 = *(const bf16x8*)(r2 + 8);
            bf16x8 c2 = *(const bf16x8*)(r2 + 16);
            bf16x8 c3 = *(const bf16x8*)(r2 + 24);
            bf16x8 d0 = *(const bf16x8*)(r3);
            bf16x8 d1 = *(const bf16x8*)(r3 + 8);
            bf16x8 d2 = *(const bf16x8*)(r3 + 16);
            bf16x8 d3 = *(const bf16x8*)(r3 + 24);
#pragma unroll
            for (int j = 0; j < 8; ++j) {
                acc[j]      += (bf2f(a0[j]) + bf2f(b0[j])) + (bf2f(c0[j]) + bf2f(d0[j]));
                acc[8 + j]  += (bf2f(a1[j]) + bf2f(b1[j])) + (bf2f(c1[j]) + bf2f(d1[j]));
                acc[16 + j] += (bf2f(a2[j]) + bf2f(b2[j])) + (bf2f(c2[j]) + bf2f(d2[j]));
                acc[24 + j] += (bf2f(a3[j]) + bf2f(b3[j])) + (bf2f(c3[j]) + bf2f(d3[j]));
            }
        }
        for (; e < dg; ++e) {
            const short* r0 = tab + (size_t)cp[e] * 128;
            bf16x8 a0 = *(const bf16x8*)(r0);
            bf16x8 a1 = *(const bf16x8*)(r0 + 8);
            bf16x8 a2 = *(const bf16x8*)(r0 + 16);
            bf16x8 a3 = *(const bf16x8*)(r0 + 24);
#pragma unroll
            for (int j = 0; j < 8; ++j) {
                acc[j]      += bf2f(a0[j]);
                acc[8 + j]  += bf2f(a1[j]);
                acc[16 + j] += bf2f(a2[j]);
                acc[24 + j] += bf2f(a3[j]);
            }
        }
        float s = 1.0f + epsArr[layer];
        const short* hs = tab + (size_t)gnode * 128;
        bf16x8 h0 = *(const bf16x8*)(hs);
        bf16x8 h1 = *(const bf16x8*)(hs + 8);
        bf16x8 h2 = *(const bf16x8*)(hs + 16);
        bf16x8 h3 = *(const bf16x8*)(hs + 24);
#pragma unroll
        for (int j = 0; j < 8; ++j) {
            acc[j]      = fmaf(s, bf2f(h0[j]), acc[j]);
            acc[8 + j]  = fmaf(s, bf2f(h1[j]), acc[8 + j]);
            acc[16 + j] = fmaf(s, bf2f(h2[j]), acc[16 + j]);
            acc[24 + j] = fmaf(s, bf2f(h3[j]), acc[24 + j]);
        }
    }
    // pack z quarter (feats q*32..+32) to bf16
    bf16x8 zp[4];
#pragma unroll
    for (int i = 0; i < 4; ++i) {
#pragma unroll
        for (int j = 0; j < 8; ++j) zp[i][j] = f2bf(acc[i * 8 + j]);
    }

    // ---- param vector staging ----
    if (t < (LAST ? 128 : 192)) {
        int which = t >> 5, chunk = t & 31;
        const float* vp = (which == 0) ? B1 : (which == 1) ? B2 : (which == 2) ? G1
                        : (which == 3) ? Bt1 : (which == 4) ? G2 : Bt2;
        *(f32x4*)(lds + 49152 + which * 512 + chunk * 16) = *(const f32x4*)(vp + chunk * 4);
    }
    // ---- stage W1 into [0,32K) and z into [32K,48K) (both swizzled) ----
#pragma unroll
    for (int i = 0; i < 8; ++i) {
        int b = i * 4096 + t * 16;
        *(bf16x8*)(lds + (b ^ (((b >> 8) & 7) << 4))) = g1[i];
    }
#pragma unroll
    for (int i = 0; i < 4; ++i)
        *(bf16x8*)(lds + 32768 + ((g * 256 + q * 64 + i * 16) ^ gswz)) = zp[i];
    __syncthreads();

    // ---- z B-fragments from LDS; issue residual loads (hide under GEMM1) ----
    bf16x8 zb0 = *(const bf16x8*)(lds + 32768 + ((lrow * 256 +   0 + kq * 16) ^ swzl));
    bf16x8 zb1 = *(const bf16x8*)(lds + 32768 + ((lrow * 256 +  64 + kq * 16) ^ swzl));
    bf16x8 zb2 = *(const bf16x8*)(lds + 32768 + ((lrow * 256 + 128 + kq * 16) ^ swzl));
    bf16x8 zb3 = *(const bf16x8*)(lds + 32768 + ((lrow * 256 + 192 + kq * 16) ^ swzl));
    f32x4 rsv[8] = {};
    if (row < N_NODES) {
#pragma unroll
        for (int ct = 0; ct < 8; ++ct)
            rsv[ct] = *(const f32x4*)(RS + (size_t)row * D + ct * 16 + kq * 4);
    }

    // ---- GEMM1 (W1 from LDS) + bias + ReLU -> p[] ----
    bf16x4 p[8];
#pragma unroll
    for (int ct = 0; ct < 8; ++ct) {
        int wb = (ct * 16 + r) * 256 + kq * 16;
        f32x4 a = {0.f, 0.f, 0.f, 0.f};
        a = __builtin_amdgcn_mfma_f32_16x16x32_bf16(*(const bf16x8*)(lds + ((wb      ) ^ swzr)), zb0, a, 0, 0, 0);
        a = __builtin_amdgcn_mfma_f32_16x16x32_bf16(*(const bf16x8*)(lds + ((wb +  64) ^ swzr)), zb1, a, 0, 0, 0);
        a = __builtin_amdgcn_mfma_f32_16x16x32_bf16(*(const bf16x8*)(lds + ((wb + 128) ^ swzr)), zb2, a, 0, 0, 0);
        a = __builtin_amdgcn_mfma_f32_16x16x32_bf16(*(const bf16x8*)(lds + ((wb + 192) ^ swzr)), zb3, a, 0, 0, 0);
        f32x4 bias = *(const f32x4*)(lds + 49152 + 0 + ct * 64 + fcol);
        p[ct][0] = f2bf(fmaxf(a[0] + bias.x, 0.0f));
        p[ct][1] = f2bf(fmaxf(a[1] + bias.y, 0.0f));
        p[ct][2] = f2bf(fmaxf(a[2] + bias.z, 0.0f));
        p[ct][3] = f2bf(fmaxf(a[3] + bias.w, 0.0f));
    }
    __syncthreads();   // W1-region and z-region reads complete

    // ---- restage W2 into [0,32K); write hid into [32K,48K) ----
#pragma unroll
    for (int i = 0; i < 8; ++i) {
        int b = i * 4096 + t * 16;
        *(bf16x8*)(lds + (b ^ (((b >> 8) & 7) << 4))) = g2[i];
    }
#pragma unroll
    for (int ct = 0; ct < 8; ++ct)
        *(bf16x4*)(lds + 32768 + ((lrow * 256 + ct * 32 + kq * 8) ^ swzl)) = p[ct];
    __syncthreads();

    // ---- hid B-fragments ----
    bf16x8 hb0 = *(const bf16x8*)(lds + 32768 + ((lrow * 256 +   0 + kq * 16) ^ swzl));
    bf16x8 hb1 = *(const bf16x8*)(lds + 32768 + ((lrow * 256 +  64 + kq * 16) ^ swzl));
    bf16x8 hb2 = *(const bf16x8*)(lds + 32768 + ((lrow * 256 + 128 + kq * 16) ^ swzl));
    bf16x8 hb3 = *(const bf16x8*)(lds + 32768 + ((lrow * 256 + 192 + kq * 16) ^ swzl));

    // ---- GEMM2 (W2 from LDS) + bias ----
    f32x4 o[8];
#pragma unroll
    for (int ct = 0; ct < 8; ++ct) {
        int wb = (ct * 16 + r) * 256 + kq * 16;
        f32x4 a = {0.f, 0.f, 0.f, 0.f};
        a = __builtin_amdgcn_mfma_f32_16x16x32_bf16(*(const bf16x8*)(lds + ((wb      ) ^ swzr)), hb0, a, 0, 0, 0);
        a = __builtin_amdgcn_mfma_f32_16x16x32_bf16(*(const bf16x8*)(lds + ((wb +  64) ^ swzr)), hb1, a, 0, 0, 0);
        a = __builtin_amdgcn_mfma_f32_16x16x32_bf16(*(const bf16x8*)(lds + ((wb + 128) ^ swzr)), hb2, a, 0, 0, 0);
        a = __builtin_amdgcn_mfma_f32_16x16x32_bf16(*(const bf16x8*)(lds + ((wb + 192) ^ swzr)), hb3, a, 0, 0, 0);
        f32x4 bias = *(const f32x4*)(lds + 49152 + 512 + ct * 64 + fcol);
        o[ct] = a + bias;
    }

    // ---- LayerNorm over the row ----
    float s = 0.f, qq = 0.f;
#pragma unroll
    for (int ct = 0; ct < 8; ++ct) {
        s  += o[ct].x + o[ct].y + o[ct].z + o[ct].w;
        qq += o[ct].x * o[ct].x + o[ct].y * o[ct].y + o[ct].z * o[ct].z + o[ct].w * o[ct].w;
    }
    s += __shfl_xor(s, 16, 64); qq += __shfl_xor(qq, 16, 64);
    s += __shfl_xor(s, 32, 64); qq += __shfl_xor(qq, 32, 64);
    float mu = s * (1.0f / D);
    float rstd = rsqrtf(qq * (1.0f / D) - mu * mu + 1e-5f);
#pragma unroll
    for (int ct = 0; ct < 8; ++ct) {
        f32x4 gv = *(const f32x4*)(lds + 49152 + 1024 + ct * 64 + fcol);
        f32x4 bv = *(const f32x4*)(lds + 49152 + 1536 + ct * 64 + fcol);
        o[ct] = (o[ct] - mu) * rstd * gv + bv;
    }

    if (!LAST) {
        float s2 = 0.f, q2 = 0.f;
#pragma unroll
        for (int ct = 0; ct < 8; ++ct) {
            s2 += o[ct].x + o[ct].y + o[ct].z + o[ct].w;
            q2 += o[ct].x * o[ct].x + o[ct].y * o[ct].y + o[ct].z * o[ct].z + o[ct].w * o[ct].w;
        }
        s2 += __shfl_xor(s2, 16, 64); q2 += __shfl_xor(q2, 16, 64);
        s2 += __shfl_xor(s2, 32, 64); q2 += __shfl_xor(q2, 32, 64);
        float mu2 = s2 * (1.0f / D);
        float rstd2 = rsqrtf(q2 * (1.0f / D) - mu2 * mu2 + 1e-5f);
#pragma unroll
        for (int ct = 0; ct < 8; ++ct) {
            f32x4 gv = *(const f32x4*)(lds + 49152 + 2048 + ct * 64 + fcol);
            f32x4 bv = *(const f32x4*)(lds + 49152 + 2560 + ct * 64 + fcol);
            f32x4 y = (o[ct] - mu2) * rstd2 * gv + bv;
            y.x = fmaxf(y.x, 0.f); y.y = fmaxf(y.y, 0.f);
            y.z = fmaxf(y.z, 0.f); y.w = fmaxf(y.w, 0.f);
            o[ct] = y;
        }
    }

    // ---- residual + store ----
    if (row < N_NODES) {
#pragma unroll
        for (int ct = 0; ct < 8; ++ct) {
            size_t off = (size_t)row * D + ct * 16 + kq * 4;
            f32x4 hv = rsv[ct] + o[ct];
            *(f32x4*)(H + off) = hv;
            if (!LAST) {
                bf16x4 pb;
                pb[0] = f2bf(hv.x); pb[1] = f2bf(hv.y); pb[2] = f2bf(hv.z); pb[3] = f2bf(hv.w);
                *(bf16x4*)(HBout + off) = pb;
            }
        }
    }
}

extern "C" void kernel_launch(void* const* d_in, const int* in_sizes, int n_in,
                              void* d_out, int out_size, void* d_ws, size_t ws_size,
                              hipStream_t stream) {
    const float* x   = (const float*)d_in[0];
    const int*   ei  = (const int*)d_in[1];
    const float* eps = (const float*)d_in[2];
    const float* W1  = (const float*)d_in[3];
    const float* b1  = (const float*)d_in[4];
    const float* W2  = (const float*)d_in[5];
    const float* b2  = (const float*)d_in[6];
    const float* lng = (const float*)d_in[7];
    const float* lnb = (const float*)d_in[8];
    const float* skg = (const float*)d_in[9];
    const float* skb = (const float*)d_in[10];
    float* h = (float*)d_out;

    char* ws = (char*)d_ws;
    short* hb0  = (short*)ws;                         // 12,800,000 B (bf16 [N][128])
    short* hb1  = (short*)(ws + 12800000);            // 12,800,000 B (ping-pong)
    short* wt   = (short*)(ws + 25600000);            //    196,608 B
    int*   rs   = (int*)  (ws + 25796608);            //    200,192 B
    int*   deg  = (int*)  (ws + 25996800);            //    200,192 B
    int*   cur  = (int*)  (ws + 26196992);            //    200,192 B
    int*   col  = (int*)  (ws + 26397184);            //  2,560,000 B
    int*   bsum = (int*)  (ws + 28957184);            //      1,024 B

    const int* srcIdx = ei;
    const int* dstIdx = ei + N_EDGES;

    init_kernel<<<(N_NODES * 32) / 256, 256, 0, stream>>>((const f32x4*)x, (bf16x4*)hb0);
    prepw_kernel<<<(6 * 16384) / 256, 256, 0, stream>>>(W1, W2, wt);

    hipMemsetAsync(deg, 0, 2 * 200192, stream);  // deg + cur contiguous
    hist_kernel<<<(N_EDGES + 255) / 256, 256, 0, stream>>>(dstIdx, deg);
    scan1_kernel<<<SCAN_NB, 256, 0, stream>>>(deg, rs, bsum);
    scan2_kernel<<<1, 256, 0, stream>>>(bsum);
    scan3_kernel<<<SCAN_NB, 256, 0, stream>>>(rs, bsum);
    fill_kernel<<<(N_EDGES + 255) / 256, 256, 0, stream>>>(srcIdx, dstIdx, rs, cur, col);

    short* hbs[2] = {hb0, hb1};
    for (int l = 0; l < LAYERS; ++l) {
        const float* rsrc = (l == 0) ? x : h;
        short* hin  = hbs[l & 1];
        short* hout = hbs[(l + 1) & 1];
        if (l < LAYERS - 1) {
            fused_kernel<false><<<NPAD / 64, 256, 0, stream>>>(
                hin, rs, deg, col, eps, l,
                wt + l * 16384, b1 + l * D, wt + (3 + l) * 16384, b2 + l * D,
                lng + l * D, lnb + l * D, skg + l * D, skb + l * D, rsrc, h, hout);
        } else {
            fused_kernel<true><<<NPAD / 64, 256, 0, stream>>>(
                hin, rs, deg, col, eps, l,
                wt + l * 16384, b1 + l * D, wt + (3 + l) * 16384, b2 + l * D,
                lng + l * D, lnb + l * D, nullptr, nullptr, rsrc, h, nullptr);
        }
    }
}